// Round 1
// baseline (230.155 us; speedup 1.0000x reference)
//
#include <hip/hip_runtime.h>
#include <hip/hip_bf16.h>
#include <math.h>

#define BDIM 512
#define DDIM 512
#define CDIM 100000
#define NC 64
#define NCHUNK ((CDIM + NC - 1) / NC)   // 1563

typedef __attribute__((ext_vector_type(8))) short short8;
typedef __attribute__((ext_vector_type(4))) float f32x4;

__device__ __forceinline__ unsigned short f2bf(float f) {
  unsigned int u = __builtin_bit_cast(unsigned int, f);
  u = (u + 0x7FFFu + ((u >> 16) & 1u)) >> 16;   // RNE
  return (unsigned short)u;
}

// ---- kernel 1: L2-normalize feature rows, emit bf16 [B][D] ----
__global__ void k_rownorm(const float* __restrict__ x, unsigned short* __restrict__ a) {
  const int b = blockIdx.x;
  const int tid = threadIdx.x;
  const float* row = x + (size_t)b * DDIM;
  float v0 = row[tid], v1 = row[tid + 256];
  float ss = v0 * v0 + v1 * v1;
  #pragma unroll
  for (int m = 1; m < 64; m <<= 1) ss += __shfl_xor(ss, m);
  __shared__ float sred[4];
  __shared__ float sinv;
  if ((tid & 63) == 0) sred[tid >> 6] = ss;
  __syncthreads();
  if (tid == 0) {
    float s = sred[0] + sred[1] + sred[2] + sred[3];
    sinv = 1.f / fmaxf(sqrtf(s), 1e-12f);
  }
  __syncthreads();
  const float inv = sinv;
  a[(size_t)b * DDIM + tid] = f2bf(v0 * inv);
  a[(size_t)b * DDIM + tid + 256] = f2bf(v1 * inv);
}

// ---- kernel 2: fused colnorm + GEMM + margin + per-chunk LSE partials ----
__global__ void k_main(const unsigned short* __restrict__ a,
                       const float* __restrict__ w,
                       const long long* __restrict__ label,
                       float2* __restrict__ part,
                       float* __restrict__ labellogit) {
  __shared__ __align__(16) unsigned short wlds[NC * DDIM];  // 64 KB, [c][d] swizzled
  __shared__ float ssred[8][NC];
  __shared__ float invwn_sh[NC];

  const int t = threadIdx.x;
  const int chunk = blockIdx.x;
  const int c0 = chunk * NC;

  // load w chunk -> bf16 LDS (swizzled), accumulate column sumsq in fp32
  {
    const int c = t & (NC - 1);
    const int dg = t >> 6;                 // == wave id; coalesced 64-float rows
    const int cg = c0 + c;
    const bool valid = cg < CDIM;
    float ss = 0.f;
    for (int d = dg; d < DDIM; d += 8) {
      float v = valid ? w[(size_t)d * CDIM + cg] : 0.f;
      ss += v * v;
      wlds[c * DDIM + (d ^ ((c & 7) << 3))] = f2bf(v);
    }
    ssred[dg][c] = ss;
  }
  __syncthreads();
  if (t < NC) {
    float s = 0.f;
    #pragma unroll
    for (int i = 0; i < 8; i++) s += ssred[i][t];
    invwn_sh[t] = 1.f / fmaxf(sqrtf(s), 1e-12f);
  }
  __syncthreads();

  const int wave = t >> 6;
  const int lane = t & 63;
  const int lhi = lane >> 4;   // 0..3
  const int llo = lane & 15;   // 0..15

  f32x4 acc[4][4];
  #pragma unroll
  for (int i = 0; i < 4; i++)
    #pragma unroll
    for (int j = 0; j < 4; j++)
      acc[i][j] = (f32x4){0.f, 0.f, 0.f, 0.f};

  // wave owns rows [wave*64, wave*64+64); A frags straight from L2-resident ws
  const unsigned short* abase = a + (size_t)(wave * 64 + llo) * DDIM + (lhi << 3);
  for (int ks = 0; ks < DDIM; ks += 32) {
    short8 af[4], bfr[4];
    #pragma unroll
    for (int rf = 0; rf < 4; rf++)
      af[rf] = *reinterpret_cast<const short8*>(abase + ks + rf * 16 * DDIM);
    const int bk = ks + (lhi << 3);
    #pragma unroll
    for (int cf = 0; cf < 4; cf++) {
      const int c = cf * 16 + llo;
      bfr[cf] = *reinterpret_cast<const short8*>(&wlds[c * DDIM + (bk ^ ((c & 7) << 3))]);
    }
    #pragma unroll
    for (int rf = 0; rf < 4; rf++)
      #pragma unroll
      for (int cf = 0; cf < 4; cf++)
        acc[rf][cf] = __builtin_amdgcn_mfma_f32_16x16x32_bf16(af[rf], bfr[cf], acc[rf][cf], 0, 0, 0);
  }

  // epilogue: logits -> per-row (max, sumexp) over this chunk's 64 classes
  #pragma unroll
  for (int rf = 0; rf < 4; rf++) {
    #pragma unroll
    for (int r = 0; r < 4; r++) {
      const int row = wave * 64 + rf * 16 + (lhi << 2) + r;
      const int lab = (int)label[row];
      float vals[4];
      float mloc = -INFINITY;
      #pragma unroll
      for (int cf = 0; cf < 4; cf++) {
        const int cg = c0 + cf * 16 + llo;
        float cs = acc[rf][cf][r] * invwn_sh[cf * 16 + llo];
        cs = fminf(fmaxf(cs, -1.f), 1.f);
        float lg = 64.f * cs;
        if (cg == lab) { lg = 64.f * (cs - 0.35f); labellogit[row] = lg; }
        if (cg >= CDIM) lg = -INFINITY;
        vals[cf] = lg;
        mloc = fmaxf(mloc, lg);
      }
      float m = mloc;
      #pragma unroll
      for (int msk = 1; msk < 16; msk <<= 1) m = fmaxf(m, __shfl_xor(m, msk));
      float s = 0.f;
      #pragma unroll
      for (int cf = 0; cf < 4; cf++) s += __expf(vals[cf] - m);
      #pragma unroll
      for (int msk = 1; msk < 16; msk <<= 1) s += __shfl_xor(s, msk);
      if (llo == 0) part[(size_t)row * NCHUNK + chunk] = make_float2(m, s);
    }
  }
}

// ---- kernel 3: per-row online-LSE combine over chunks ----
__global__ void k_rowreduce(const float2* __restrict__ part,
                            const float* __restrict__ labellogit,
                            float* __restrict__ rowloss) {
  const int row = blockIdx.x;
  const int tid = threadIdx.x;
  float m = -INFINITY, s = 0.f;
  for (int ch = tid; ch < NCHUNK; ch += 256) {
    float2 p = part[(size_t)row * NCHUNK + ch];
    float nm = fmaxf(m, p.x);
    s = s * __expf(m - nm) + p.y * __expf(p.x - nm);
    m = nm;
  }
  #pragma unroll
  for (int msk = 1; msk < 64; msk <<= 1) {
    float om = __shfl_xor(m, msk), os = __shfl_xor(s, msk);
    float nm = fmaxf(m, om);
    s = s * __expf(m - nm) + os * __expf(om - nm);
    m = nm;
  }
  __shared__ float sm[4], ssum[4];
  const int wv = tid >> 6, ln = tid & 63;
  if (ln == 0) { sm[wv] = m; ssum[wv] = s; }
  __syncthreads();
  if (tid == 0) {
    float M = sm[0], S = ssum[0];
    #pragma unroll
    for (int i = 1; i < 4; i++) {
      float nm = fmaxf(M, sm[i]);
      S = S * __expf(M - nm) + ssum[i] * __expf(sm[i] - nm);
      M = nm;
    }
    rowloss[row] = M + logf(S) - labellogit[row];
  }
}

// ---- kernel 4: mean over rows -> scalar ----
__global__ void k_mean(const float* __restrict__ rowloss, float* __restrict__ out) {
  const int tid = threadIdx.x;
  float v = rowloss[tid];
  #pragma unroll
  for (int msk = 1; msk < 64; msk <<= 1) v += __shfl_xor(v, msk);
  __shared__ float sred[8];
  if ((tid & 63) == 0) sred[tid >> 6] = v;
  __syncthreads();
  if (tid == 0) {
    float s = 0.f;
    #pragma unroll
    for (int i = 0; i < 8; i++) s += sred[i];
    out[0] = s / (float)BDIM;
  }
}

extern "C" void kernel_launch(void* const* d_in, const int* in_sizes, int n_in,
                              void* d_out, int out_size, void* d_ws, size_t ws_size,
                              hipStream_t stream) {
  const float* input = (const float*)d_in[0];
  const long long* label = (const long long*)d_in[1];
  const float* w = (const float*)d_in[2];
  float* out = (float*)d_out;

  char* ws = (char*)d_ws;
  unsigned short* a_bf16 = (unsigned short*)ws;                       // 512 KB
  float2* part = (float2*)(ws + 512 * 1024);                          // B*NCHUNK*8 = 6.4 MB
  float* labellogit = (float*)(ws + 512 * 1024 + (size_t)BDIM * NCHUNK * sizeof(float2));
  float* rowloss = labellogit + BDIM;

  k_rownorm<<<BDIM, 256, 0, stream>>>(input, a_bf16);
  k_main<<<NCHUNK, 512, 0, stream>>>(a_bf16, w, label, part, labellogit);
  k_rowreduce<<<BDIM, 256, 0, stream>>>(part, labellogit, rowloss);
  k_mean<<<1, BDIM, 0, stream>>>(rowloss, out);
}